// Round 8
// baseline (112.003 us; speedup 1.0000x reference)
//
#include <hip/hip_runtime.h>

#define DIM 256
#define BATCH 131072
#define BM 64            // rows per block; 4 waves, each: all 64 rows x its 64-col group

typedef __attribute__((ext_vector_type(8))) short s16x8;          // 8 bf16 (4 VGPRs)
typedef __attribute__((ext_vector_type(8))) unsigned short u16x8; // 16B
typedef __attribute__((ext_vector_type(4))) float f32x4;

static __device__ __forceinline__ unsigned short f2bf(float f) {
    unsigned int u = __builtin_bit_cast(unsigned int, f);
    u = (u + 0x7FFFu + ((u >> 16) & 1u)) >> 16;   // round-to-nearest-even
    return (unsigned short)u;
}

static __device__ __forceinline__ s16x8 cvt8(const float4 a, const float4 b) {
    return (s16x8){ (short)f2bf(a.x), (short)f2bf(a.y), (short)f2bf(a.z), (short)f2bf(a.w),
                    (short)f2bf(b.x), (short)f2bf(b.y), (short)f2bf(b.z), (short)f2bf(b.w) };
}

// ---- fused: m = l@u ; w = p@m ; store bf16 w in MFMA-fragment order ----
// elem (d,k) -> ((d>>4)*8 + (k>>5))*512 + (((k>>3)&3)*16 + (d&15))*8 + (k&7)
__global__ void lu_perm(const float* __restrict__ l, const float* __restrict__ u,
                        const float* __restrict__ p, unsigned short* __restrict__ wpk) {
    __shared__ float sL[DIM];
    __shared__ int dest;
    const int i = blockIdx.x, j = threadIdx.x;
    sL[j] = l[i * DIM + j];
    if (p[j * DIM + i] != 0.0f) dest = j;   // row i of l@u -> row dest of w
    __syncthreads();
    float s0 = 0.f, s1 = 0.f, s2 = 0.f, s3 = 0.f;
    #pragma unroll 4
    for (int k = 0; k < DIM; k += 4) {
        s0 = fmaf(sL[k + 0], u[(k + 0) * DIM + j], s0);
        s1 = fmaf(sL[k + 1], u[(k + 1) * DIM + j], s1);
        s2 = fmaf(sL[k + 2], u[(k + 2) * DIM + j], s2);
        s3 = fmaf(sL[k + 3], u[(k + 3) * DIM + j], s3);
    }
    const int d = dest;
    const int idx = ((d >> 4) * 8 + (j >> 5)) * 512 + (((j >> 3) & 3) * 16 + (d & 15)) * 8 + (j & 7);
    wpk[idx] = f2bf((s0 + s1) + (s2 + s3));
}

// ---------------- log_det = sum log|diag(u)| ----------------
__global__ void logdet_kernel(const float* __restrict__ u, float* __restrict__ out) {
    const int i = threadIdx.x;
    float v = logf(fabsf(u[i * DIM + i]));
    #pragma unroll
    for (int o = 32; o; o >>= 1) v += __shfl_down(v, o, 64);
    __shared__ float partial[4];
    if ((i & 63) == 0) partial[i >> 6] = v;
    __syncthreads();
    if (i == 0) out[0] = (partial[0] + partial[1]) + (partial[2] + partial[3]);
}

// ---- DIAGNOSTIC: ideal-pattern x -> y copy (read 134 MB + write 134 MB) ----
// Measures the mixed read+write stream ceiling for exactly our footprint.
// Launched BEFORE the real gemm, which fully overwrites d_out -> harmless.
__global__ __launch_bounds__(256) void xcopy(const float4* __restrict__ src,
                                             float4* __restrict__ dst) {
    const int i = blockIdx.x * 256 + threadIdx.x;   // 2048 blocks -> stride 524288
    float4 v[16];
    #pragma unroll
    for (int r = 0; r < 16; r++) v[r] = src[i + r * 524288];
    #pragma unroll
    for (int r = 0; r < 16; r++) dst[i + r * 524288] = v[r];
}

// ---------------- y = x @ w^T (R4 exact: best-known anchor) ----------------
__global__ __launch_bounds__(256, 3) void gemm_xwT(const float* __restrict__ x,
                                                   const unsigned short* __restrict__ wpk,
                                                   float* __restrict__ y) {
    __shared__ unsigned short sA[4 * 8 * 512];   // 32 KB: [mb][ks][lane''][8]

    const int t    = threadIdx.x;
    const int lane = t & 63;
    const int wc   = t >> 6;        // 0..3 : 64-col group (also mb for staging)
    const int lr   = lane & 15;
    const int lg   = lane >> 4;
    const long row0 = (long)blockIdx.x * BM;

    // ---- single-shot A staging: thread t covers row sr, cols kq*8 + q*32 ----
    const int sr  = t >> 2;         // 0..63
    const int kq  = t & 3;
    const int r15 = sr & 15;
    const int mb  = t >> 6;         // == sr>>4 == wave id
    const float* asrc = x + (row0 + sr) * DIM + kq * 8;
    const int lpx = (kq * 16 + r15) ^ (kq << 1);   // lane' ^ lane'-dependent XOR part
    #pragma unroll
    for (int q = 0; q < 8; ++q) {   // q == ks for this thread's writes
        const float4 v0 = *(const float4*)(asrc + q * 32);
        const float4 v1 = *(const float4*)(asrc + q * 32 + 4);
        *(s16x8*)&sA[(mb * 8 + q) * 512 + (lpx ^ q) * 8] = cvt8(v0, v1);
    }

    // ---- B: frag-packed, L2-resident; double-buffered register prefetch ----
    const unsigned short* bbase = wpk + wc * 4 * 8 * 512 + lane * 8;  // + (n*8+ks)*512
    const int lx = lane ^ ((lane >> 4) << 1);      // read-side XOR (ks applied per step)

    f32x4 acc[4][4];
    #pragma unroll
    for (int mi = 0; mi < 4; mi++)
        #pragma unroll
        for (int n = 0; n < 4; n++) acc[mi][n] = (f32x4){0.f, 0.f, 0.f, 0.f};

    s16x8 bf[2][4];
    #pragma unroll
    for (int n = 0; n < 4; n++)
        bf[0][n] = __builtin_bit_cast(s16x8, *(const u16x8*)(bbase + n * 8 * 512));

    __syncthreads();   // the ONLY pre-compute barrier

    #pragma unroll
    for (int ks = 0; ks < 8; ++ks) {
        if (ks < 7) {
            #pragma unroll
            for (int n = 0; n < 4; n++)
                bf[(ks + 1) & 1][n] = __builtin_bit_cast(s16x8,
                    *(const u16x8*)(bbase + (n * 8 + ks + 1) * 512));
        }
        s16x8 af[4];
        #pragma unroll
        for (int mi = 0; mi < 4; mi++)
            af[mi] = *(const s16x8*)&sA[(mi * 8 + ks) * 512 + (lx ^ ks) * 8];
        #pragma unroll
        for (int mi = 0; mi < 4; mi++)
            #pragma unroll
            for (int n = 0; n < 4; n++)
                acc[mi][n] = __builtin_amdgcn_mfma_f32_16x16x32_bf16(
                    af[mi], bf[ks & 1][n], acc[mi][n], 0, 0, 0);
    }

    __syncthreads();   // all waves done reading sA before reuse

    // ---- epilogue: per-wave LDS transpose -> full-row float4 stores ----
    float* ep = (float*)sA + wc * 1088;            // 16 x 68 f32 region per wave
    #pragma unroll
    for (int mi = 0; mi < 4; ++mi) {
        #pragma unroll
        for (int n = 0; n < 4; n++)
            #pragma unroll
            for (int j = 0; j < 4; j++)
                ep[(lg * 4 + j) * 68 + n * 16 + lr] = acc[mi][n][j];
        // per-wave in-order DS: reads below see this wave's writes
        #pragma unroll
        for (int it = 0; it < 4; ++it) {
            const int row = it * 4 + lg;           // 0..15
            const float4 v = *(const float4*)&ep[row * 68 + lr * 4];
            *(float4*)&y[(row0 + mi * 16 + row) * DIM + wc * 64 + lr * 4] = v;
        }
    }
}

extern "C" void kernel_launch(void* const* d_in, const int* in_sizes, int n_in,
                              void* d_out, int out_size, void* d_ws, size_t ws_size,
                              hipStream_t stream) {
    const float* x = (const float*)d_in[0];
    const float* p = (const float*)d_in[1];
    const float* l = (const float*)d_in[2];
    const float* u = (const float*)d_in[3];
    float* out = (float*)d_out;

    unsigned short* wpk = (unsigned short*)d_ws;   // 128 KB frag-packed bf16 w

    lu_perm<<<DIM, DIM, 0, stream>>>(l, u, p, wpk);
    logdet_kernel<<<1, DIM, 0, stream>>>(u, out + (size_t)BATCH * DIM);
    // diagnostic stream-ceiling probe (output overwritten by gemm below)
    xcopy<<<2048, 256, 0, stream>>>((const float4*)x, (float4*)out);
    gemm_xwT<<<BATCH / BM, 256, 0, stream>>>(x, wpk, out);
}

// Round 9
// 61.218 us; speedup vs baseline: 1.8296x; 1.8296x over previous
//
#include <hip/hip_runtime.h>

#define DIM 256
#define BATCH 131072
#define BM 64            // rows per block; 4 waves, each: all 64 rows x its 64-col group

typedef __attribute__((ext_vector_type(8))) short s16x8;          // 8 bf16 (4 VGPRs)
typedef __attribute__((ext_vector_type(8))) unsigned short u16x8; // 16B
typedef __attribute__((ext_vector_type(4))) float f32x4;

static __device__ __forceinline__ unsigned short f2bf(float f) {
    unsigned int u = __builtin_bit_cast(unsigned int, f);
    u = (u + 0x7FFFu + ((u >> 16) & 1u)) >> 16;   // round-to-nearest-even
    return (unsigned short)u;
}

static __device__ __forceinline__ s16x8 cvt8(const float4 a, const float4 b) {
    return (s16x8){ (short)f2bf(a.x), (short)f2bf(a.y), (short)f2bf(a.z), (short)f2bf(a.w),
                    (short)f2bf(b.x), (short)f2bf(b.y), (short)f2bf(b.z), (short)f2bf(b.w) };
}

// ---- fused: m = l@u ; w = p@m ; bf16 frag-pack ; block 0 also does logdet ----
// elem (d,k) -> ((d>>4)*8 + (k>>5))*512 + (((k>>3)&3)*16 + (d&15))*8 + (k&7)
__global__ void lu_perm(const float* __restrict__ l, const float* __restrict__ u,
                        const float* __restrict__ p, unsigned short* __restrict__ wpk,
                        float* __restrict__ logdet_out) {
    __shared__ float sL[DIM];
    __shared__ int dest;
    __shared__ float partial[4];
    const int i = blockIdx.x, j = threadIdx.x;
    sL[j] = l[i * DIM + j];
    if (p[j * DIM + i] != 0.0f) dest = j;   // row i of l@u -> row dest of w
    __syncthreads();
    float s0 = 0.f, s1 = 0.f, s2 = 0.f, s3 = 0.f;
    #pragma unroll 4
    for (int k = 0; k < DIM; k += 4) {
        s0 = fmaf(sL[k + 0], u[(k + 0) * DIM + j], s0);
        s1 = fmaf(sL[k + 1], u[(k + 1) * DIM + j], s1);
        s2 = fmaf(sL[k + 2], u[(k + 2) * DIM + j], s2);
        s3 = fmaf(sL[k + 3], u[(k + 3) * DIM + j], s3);
    }
    const int d = dest;
    const int idx = ((d >> 4) * 8 + (j >> 5)) * 512 + (((j >> 3) & 3) * 16 + (d & 15)) * 8 + (j & 7);
    wpk[idx] = f2bf((s0 + s1) + (s2 + s3));

    // ---- block 0: log_det = sum log|diag(u)| (fused to save a launch) ----
    if (i == 0) {
        float v = logf(fabsf(u[j * DIM + j]));
        #pragma unroll
        for (int o = 32; o; o >>= 1) v += __shfl_down(v, o, 64);
        if ((j & 63) == 0) partial[j >> 6] = v;
        __syncthreads();
        if (j == 0) logdet_out[0] = (partial[0] + partial[1]) + (partial[2] + partial[3]);
    }
}

// ---------------- y = x @ w^T (R4 anchor: single-shot swizzled A-stage, ----
// ---------------- barrier-free K-loop, LDS-transposed float4 epilogue) ----
__global__ __launch_bounds__(256, 3) void gemm_xwT(const float* __restrict__ x,
                                                   const unsigned short* __restrict__ wpk,
                                                   float* __restrict__ y) {
    __shared__ unsigned short sA[4 * 8 * 512];   // 32 KB: [mb][ks][lane''][8]

    const int t    = threadIdx.x;
    const int lane = t & 63;
    const int wc   = t >> 6;        // 0..3 : 64-col group (also mb for staging)
    const int lr   = lane & 15;
    const int lg   = lane >> 4;
    const long row0 = (long)blockIdx.x * BM;

    // ---- single-shot A staging: thread t covers row sr, cols kq*8 + q*32 ----
    const int sr  = t >> 2;         // 0..63
    const int kq  = t & 3;
    const int r15 = sr & 15;
    const int mb  = t >> 6;         // == sr>>4 == wave id
    const float* asrc = x + (row0 + sr) * DIM + kq * 8;
    const int lpx = (kq * 16 + r15) ^ (kq << 1);   // lane' ^ lane'-dependent XOR part
    #pragma unroll
    for (int q = 0; q < 8; ++q) {   // q == ks for this thread's writes
        const float4 v0 = *(const float4*)(asrc + q * 32);
        const float4 v1 = *(const float4*)(asrc + q * 32 + 4);
        *(s16x8*)&sA[(mb * 8 + q) * 512 + (lpx ^ q) * 8] = cvt8(v0, v1);
    }

    // ---- B: frag-packed, L2-resident; double-buffered register prefetch ----
    const unsigned short* bbase = wpk + wc * 4 * 8 * 512 + lane * 8;  // + (n*8+ks)*512
    const int lx = lane ^ ((lane >> 4) << 1);      // read-side XOR (ks applied per step)

    f32x4 acc[4][4];
    #pragma unroll
    for (int mi = 0; mi < 4; mi++)
        #pragma unroll
        for (int n = 0; n < 4; n++) acc[mi][n] = (f32x4){0.f, 0.f, 0.f, 0.f};

    s16x8 bf[2][4];
    #pragma unroll
    for (int n = 0; n < 4; n++)
        bf[0][n] = __builtin_bit_cast(s16x8, *(const u16x8*)(bbase + n * 8 * 512));

    __syncthreads();   // the ONLY pre-compute barrier

    #pragma unroll
    for (int ks = 0; ks < 8; ++ks) {
        if (ks < 7) {
            #pragma unroll
            for (int n = 0; n < 4; n++)
                bf[(ks + 1) & 1][n] = __builtin_bit_cast(s16x8,
                    *(const u16x8*)(bbase + (n * 8 + ks + 1) * 512));
        }
        s16x8 af[4];
        #pragma unroll
        for (int mi = 0; mi < 4; mi++)
            af[mi] = *(const s16x8*)&sA[(mi * 8 + ks) * 512 + (lx ^ ks) * 8];
        #pragma unroll
        for (int mi = 0; mi < 4; mi++)
            #pragma unroll
            for (int n = 0; n < 4; n++)
                acc[mi][n] = __builtin_amdgcn_mfma_f32_16x16x32_bf16(
                    af[mi], bf[ks & 1][n], acc[mi][n], 0, 0, 0);
    }

    __syncthreads();   // all waves done reading sA before reuse

    // ---- epilogue: per-wave LDS transpose -> full-row float4 stores ----
    float* ep = (float*)sA + wc * 1088;            // 16 x 68 f32 region per wave
    #pragma unroll
    for (int mi = 0; mi < 4; ++mi) {
        #pragma unroll
        for (int n = 0; n < 4; n++)
            #pragma unroll
            for (int j = 0; j < 4; j++)
                ep[(lg * 4 + j) * 68 + n * 16 + lr] = acc[mi][n][j];
        // per-wave in-order DS: reads below see this wave's writes
        #pragma unroll
        for (int it = 0; it < 4; ++it) {
            const int row = it * 4 + lg;           // 0..15
            const float4 v = *(const float4*)&ep[row * 68 + lr * 4];
            *(float4*)&y[(row0 + mi * 16 + row) * DIM + wc * 64 + lr * 4] = v;
        }
    }
}

extern "C" void kernel_launch(void* const* d_in, const int* in_sizes, int n_in,
                              void* d_out, int out_size, void* d_ws, size_t ws_size,
                              hipStream_t stream) {
    const float* x = (const float*)d_in[0];
    const float* p = (const float*)d_in[1];
    const float* l = (const float*)d_in[2];
    const float* u = (const float*)d_in[3];
    float* out = (float*)d_out;

    unsigned short* wpk = (unsigned short*)d_ws;   // 128 KB frag-packed bf16 w

    lu_perm<<<DIM, DIM, 0, stream>>>(l, u, p, wpk, out + (size_t)BATCH * DIM);
    gemm_xwT<<<BATCH / BM, 256, 0, stream>>>(x, wpk, out);
}

// Round 11
// 60.984 us; speedup vs baseline: 1.8366x; 1.0038x over previous
//
#include <hip/hip_runtime.h>

#define DIM 256
#define BATCH 131072
#define BM 32            // rows per block; 4 waves, each: all 32 rows x its 64-col group

typedef __attribute__((ext_vector_type(8))) short s16x8;          // 8 bf16 (4 VGPRs)
typedef __attribute__((ext_vector_type(8))) unsigned short u16x8; // 16B
typedef __attribute__((ext_vector_type(4))) float f32x4;

static __device__ __forceinline__ unsigned short f2bf(float f) {
    unsigned int u = __builtin_bit_cast(unsigned int, f);
    u = (u + 0x7FFFu + ((u >> 16) & 1u)) >> 16;   // round-to-nearest-even
    return (unsigned short)u;
}

static __device__ __forceinline__ s16x8 cvt8(const float4 a, const float4 b) {
    return (s16x8){ (short)f2bf(a.x), (short)f2bf(a.y), (short)f2bf(a.z), (short)f2bf(a.w),
                    (short)f2bf(b.x), (short)f2bf(b.y), (short)f2bf(b.z), (short)f2bf(b.w) };
}

// ---- fused: m = l@u ; w = p@m ; bf16 frag-pack ; block 0 also does logdet ----
// elem (d,k) -> ((d>>4)*8 + (k>>5))*512 + (((k>>3)&3)*16 + (d&15))*8 + (k&7)
__global__ void lu_perm(const float* __restrict__ l, const float* __restrict__ u,
                        const float* __restrict__ p, unsigned short* __restrict__ wpk,
                        float* __restrict__ logdet_out) {
    __shared__ float sL[DIM];
    __shared__ int dest;
    __shared__ float partial[4];
    const int i = blockIdx.x, j = threadIdx.x;
    sL[j] = l[i * DIM + j];
    if (p[j * DIM + i] != 0.0f) dest = j;   // row i of l@u -> row dest of w
    __syncthreads();
    float s0 = 0.f, s1 = 0.f, s2 = 0.f, s3 = 0.f;
    #pragma unroll 4
    for (int k = 0; k < DIM; k += 4) {
        s0 = fmaf(sL[k + 0], u[(k + 0) * DIM + j], s0);
        s1 = fmaf(sL[k + 1], u[(k + 1) * DIM + j], s1);
        s2 = fmaf(sL[k + 2], u[(k + 2) * DIM + j], s2);
        s3 = fmaf(sL[k + 3], u[(k + 3) * DIM + j], s3);
    }
    const int d = dest;
    const int idx = ((d >> 4) * 8 + (j >> 5)) * 512 + (((j >> 3) & 3) * 16 + (d & 15)) * 8 + (j & 7);
    wpk[idx] = f2bf((s0 + s1) + (s2 + s3));

    // ---- block 0: log_det = sum log|diag(u)| (fused to save a launch) ----
    if (i == 0) {
        float v = logf(fabsf(u[j * DIM + j]));
        #pragma unroll
        for (int o = 32; o; o >>= 1) v += __shfl_down(v, o, 64);
        if ((j & 63) == 0) partial[j >> 6] = v;
        __syncthreads();
        if (j == 0) logdet_out[0] = (partial[0] + partial[1]) + (partial[2] + partial[3]);
    }
}

// ---------------- y = x @ w^T (R4 structure, BM=32 for occupancy) ----------------
// Single lever vs R9: halve block granularity (4096 blocks, launch_bounds(256,5))
// -> more co-resident blocks -> finer interleave of the phase-serial
// {read burst, compute, write burst} across each CU.
// sA sized for max(staging 16*512 shorts = 16 KB, epilogue 4*1088 f32 = 17408 B).
__global__ __launch_bounds__(256, 5) void gemm_xwT(const float* __restrict__ x,
                                                   const unsigned short* __restrict__ wpk,
                                                   float* __restrict__ y) {
    __shared__ unsigned short sA[8704];   // 17408 B

    const int t    = threadIdx.x;
    const int lane = t & 63;
    const int wc   = t >> 6;        // 0..3 : 64-col group
    const int lr   = lane & 15;
    const int lg   = lane >> 4;
    const long row0 = (long)blockIdx.x * BM;

    // ---- single-shot A staging: thread t covers row sr, cols kq*8 + q*64 ----
    const int sr  = t >> 3;         // 0..31
    const int kq  = t & 7;          // 8 threads per row
    const int r15 = sr & 15;
    const int smi = sr >> 4;        // 0..1
    const float* asrc = x + (row0 + sr) * DIM + kq * 8;
    const int slg  = kq & 3;                        // frag lane-group of this chunk
    const int ksb  = kq >> 2;                       // ks low bit contribution
    const int lpx  = (slg * 16 + r15) ^ (slg << 1); // lane' ^ lg-XOR (ks applied per q)
    #pragma unroll
    for (int q = 0; q < 4; ++q) {   // ks = q*2 + ksb for this thread's chunk
        const int ks = q * 2 + ksb;
        const float4 v0 = *(const float4*)(asrc + q * 64);
        const float4 v1 = *(const float4*)(asrc + q * 64 + 4);
        *(s16x8*)&sA[(ks * 2 + smi) * 512 + (lpx ^ ks) * 8] = cvt8(v0, v1);
    }

    // ---- B: frag-packed, L2-resident; double-buffered register prefetch ----
    const unsigned short* bbase = wpk + wc * 4 * 8 * 512 + lane * 8;  // + (n*8+ks)*512
    const int lx = lane ^ ((lane >> 4) << 1);      // read-side XOR (ks applied per step)

    f32x4 acc[2][4];
    #pragma unroll
    for (int mi = 0; mi < 2; mi++)
        #pragma unroll
        for (int n = 0; n < 4; n++) acc[mi][n] = (f32x4){0.f, 0.f, 0.f, 0.f};

    s16x8 bf[2][4];
    #pragma unroll
    for (int n = 0; n < 4; n++)
        bf[0][n] = __builtin_bit_cast(s16x8, *(const u16x8*)(bbase + n * 8 * 512));

    __syncthreads();   // the ONLY pre-compute barrier

    #pragma unroll
    for (int ks = 0; ks < 8; ++ks) {
        if (ks < 7) {
            #pragma unroll
            for (int n = 0; n < 4; n++)
                bf[(ks + 1) & 1][n] = __builtin_bit_cast(s16x8,
                    *(const u16x8*)(bbase + (n * 8 + ks + 1) * 512));
        }
        s16x8 af[2];
        #pragma unroll
        for (int mi = 0; mi < 2; mi++)
            af[mi] = *(const s16x8*)&sA[(ks * 2 + mi) * 512 + ((lx ^ ks)) * 8];
        #pragma unroll
        for (int mi = 0; mi < 2; mi++)
            #pragma unroll
            for (int n = 0; n < 4; n++)
                acc[mi][n] = __builtin_amdgcn_mfma_f32_16x16x32_bf16(
                    af[mi], bf[ks & 1][n], acc[mi][n], 0, 0, 0);
    }

    __syncthreads();   // all waves done reading sA before epilogue reuse

    // ---- epilogue: per-wave LDS transpose -> full-row float4 stores ----
    float* ep = (float*)sA + wc * 1088;            // 16 x 68 f32 region per wave
    #pragma unroll
    for (int mi = 0; mi < 2; ++mi) {
        #pragma unroll
        for (int n = 0; n < 4; n++)
            #pragma unroll
            for (int j = 0; j < 4; j++)
                ep[(lg * 4 + j) * 68 + n * 16 + lr] = acc[mi][n][j];
        // per-wave in-order DS: reads below see this wave's writes
        #pragma unroll
        for (int it = 0; it < 4; ++it) {
            const int row = it * 4 + lg;           // 0..15
            const float4 v = *(const float4*)&ep[row * 68 + lr * 4];
            *(float4*)&y[(row0 + mi * 16 + row) * DIM + wc * 64 + lr * 4] = v;
        }
    }
}

extern "C" void kernel_launch(void* const* d_in, const int* in_sizes, int n_in,
                              void* d_out, int out_size, void* d_ws, size_t ws_size,
                              hipStream_t stream) {
    const float* x = (const float*)d_in[0];
    const float* p = (const float*)d_in[1];
    const float* l = (const float*)d_in[2];
    const float* u = (const float*)d_in[3];
    float* out = (float*)d_out;

    unsigned short* wpk = (unsigned short*)d_ws;   // 128 KB frag-packed bf16 w

    lu_perm<<<DIM, DIM, 0, stream>>>(l, u, p, wpk, out + (size_t)BATCH * DIM);
    gemm_xwT<<<BATCH / BM, 256, 0, stream>>>(x, wpk, out);
}